// Round 1
// baseline (129.158 us; speedup 1.0000x reference)
//
#include <hip/hip_runtime.h>

// RelativePositionEncoding (AF3-style), B=1, N=1024, C_PAIR=128
// D_TOK = 66 rows (Wp), next 66 rows (Wt), 1 row w_ent, 6 rows (Wc). D_IN=139.

#define C_PAIR 128
#define PAIRS_PER_BLOCK 8

__global__ __launch_bounds__(256) void rpe_kernel(
    const int* __restrict__ res, const int* __restrict__ tok,
    const int* __restrict__ asym, const int* __restrict__ ent,
    const int* __restrict__ sym, const float* __restrict__ W,
    float* __restrict__ out, int N, int blocks_per_row)
{
    const int bid = blockIdx.x;
    const int i  = bid / blocks_per_row;
    const int jb = bid - i * blocks_per_row;
    const int t  = threadIdx.x;
    const int j  = jb * PAIRS_PER_BLOCK + (t >> 5);
    const int c4 = t & 31;

    // per-pair scalars (broadcast across the 32 lanes of each pair-group)
    const int ri = res[i],  rj = res[j];
    const int ai = asym[i], aj = asym[j];
    const int ei = ent[i],  ej = ent[j];
    const int ti = tok[i],  tj = tok[j];
    const int si = sym[i],  sj = sym[j];

    const bool sr = (ri == rj);
    const bool sc = (ai == aj);
    const bool se = (ei == ej);

    // idx_pos: off = ri-rj == 0 whenever sr, so clip(0+32,0,64)=32; else sentinel 65
    const int idx_pos = sr ? 32 : 65;

    int dt = ti - tj + 32;
    dt = dt < 0 ? 0 : (dt > 64 ? 64 : dt);
    const int idx_tok = (sr && sc) ? dt : 65;

    int dc = si - sj + 2;
    dc = dc < 0 ? 0 : (dc > 4 ? 4 : dc);
    const int idx_chain = (!sc) ? dc : 5;

    const float4* __restrict__ Wp = (const float4*)(W + (size_t)idx_pos * C_PAIR) + c4;
    const float4* __restrict__ Wt = (const float4*)(W + (size_t)(66 + idx_tok) * C_PAIR) + c4;
    const float4* __restrict__ We = (const float4*)(W + (size_t)132 * C_PAIR) + c4;
    const float4* __restrict__ Wc = (const float4*)(W + (size_t)(133 + idx_chain) * C_PAIR) + c4;

    const float4 p = *Wp;
    const float4 tk = *Wt;
    const float4 e = *We;
    const float4 c = *Wc;
    const float fe = se ? 1.0f : 0.0f;

    float4 r;
    r.x = ((p.x + tk.x) + fe * e.x) + c.x;
    r.y = ((p.y + tk.y) + fe * e.y) + c.y;
    r.z = ((p.z + tk.z) + fe * e.z) + c.z;
    r.w = ((p.w + tk.w) + fe * e.w) + c.w;

    float4* __restrict__ o = (float4*)(out + ((size_t)i * N + j) * C_PAIR) + c4;
    *o = r;
}

extern "C" void kernel_launch(void* const* d_in, const int* in_sizes, int n_in,
                              void* d_out, int out_size, void* d_ws, size_t ws_size,
                              hipStream_t stream) {
    const int* res  = (const int*)d_in[0];
    const int* tok  = (const int*)d_in[1];
    const int* asym = (const int*)d_in[2];
    const int* ent  = (const int*)d_in[3];
    const int* sym  = (const int*)d_in[4];
    const float* W  = (const float*)d_in[5];
    float* out = (float*)d_out;

    const int N = in_sizes[0];                 // B=1, tokens
    const int blocks_per_row = N / PAIRS_PER_BLOCK;  // N divisible by 8
    const int grid = N * blocks_per_row;

    rpe_kernel<<<grid, 256, 0, stream>>>(res, tok, asym, ent, sym, W, out, N, blocks_per_row);
}

// Round 3
// 101.384 us; speedup vs baseline: 1.2739x; 1.2739x over previous
//
#include <hip/hip_runtime.h>

// RelativePositionEncoding (AF3-style), B=1, N=1024, C_PAIR=128
// W rows: Wp = 0..65, Wt = 66..131, w_ent = 132, Wc = 133..138 (D_IN = 139)

#define C_PAIR 128
#define N_COMBO 152

typedef float f4 __attribute__((ext_vector_type(4)));

// combo id encoding (covers every reachable (idx_pos, idx_tok, idx_chain, se)):
//   same-chain & same-residue : cid = clamp(ti-tj+32,0,64) + se*65        -> [0,129]
//   same-chain & !same-residue: cid = 130 + se                            -> [130,131]
//   diff-chain                : cid = 132 + clamp(si-sj+2,0,4) + sr*5 + se*10 -> [132,151]
__device__ __forceinline__ int combo_id(int ri, int ai, int ei, int ti, int si,
                                        int rj, int aj, int ej, int tj, int sj) {
    const bool sr = (ri == rj);
    const bool sc = (ai == aj);
    const bool se = (ei == ej);
    int cid;
    if (sc) {
        if (sr) {
            int dt = ti - tj + 32;
            dt = dt < 0 ? 0 : (dt > 64 ? 64 : dt);
            cid = dt + (se ? 65 : 0);
        } else {
            cid = 130 + (se ? 1 : 0);
        }
    } else {
        int dc = si - sj + 2;
        dc = dc < 0 ? 0 : (dc > 4 ? 4 : dc);
        cid = 132 + dc + (sr ? 5 : 0) + (se ? 10 : 0);
    }
    return cid;
}

// Pass 1: build combined table T[cid][c] = ((Wp + Wt) + se*w_ent) + Wc
// (same fp32 add order as the reference -> bit-identical)
__global__ __launch_bounds__(128) void rpe_combine(const float* __restrict__ W,
                                                   float* __restrict__ T) {
    const int cid = blockIdx.x;
    const int c   = threadIdx.x;
    int idx_pos, idx_tok, idx_chain, se;
    if (cid < 130) {
        se = cid >= 65 ? 1 : 0;
        idx_pos = 32; idx_tok = cid - se * 65; idx_chain = 5;
    } else if (cid < 132) {
        se = cid - 130;
        idx_pos = 65; idx_tok = 65; idx_chain = 5;
    } else {
        int r = cid - 132;
        se = r >= 10 ? 1 : 0; r -= se * 10;
        const int sr = r >= 5 ? 1 : 0; r -= sr * 5;
        idx_pos = sr ? 32 : 65; idx_tok = 65; idx_chain = r;
    }
    const float p  = W[idx_pos * C_PAIR + c];
    const float t  = W[(66 + idx_tok) * C_PAIR + c];
    const float e  = W[132 * C_PAIR + c];
    const float ch = W[(133 + idx_chain) * C_PAIR + c];
    const float fe = se ? 1.0f : 0.0f;
    T[cid * C_PAIR + c] = ((p + t) + fe * e) + ch;
}

// Pass 2: per thread, 2 pairs: compute cid, 1 f4 table load + 1 nt f4 store each.
// Block = 16 consecutive pairs of one row i.
__global__ __launch_bounds__(256) void rpe_apply(
    const int* __restrict__ res, const int* __restrict__ tok,
    const int* __restrict__ asym, const int* __restrict__ ent,
    const int* __restrict__ sym, const float* __restrict__ T,
    float* __restrict__ out, int N, int blocks_per_row)
{
    const int bid = blockIdx.x;
    const int i   = bid / blocks_per_row;
    const int jb  = bid - i * blocks_per_row;
    const int t   = threadIdx.x;
    const int c4  = t & 31;
    const int j1  = jb * 16 + (t >> 5);
    const int j2  = j1 + 8;

    const int ri = res[i], ai = asym[i], ei = ent[i], ti = tok[i], si = sym[i];

    const int cid1 = combo_id(ri, ai, ei, ti, si, res[j1], asym[j1], ent[j1], tok[j1], sym[j1]);
    const int cid2 = combo_id(ri, ai, ei, ti, si, res[j2], asym[j2], ent[j2], tok[j2], sym[j2]);

    const f4 v1 = ((const f4*)(T + (size_t)cid1 * C_PAIR))[c4];
    const f4 v2 = ((const f4*)(T + (size_t)cid2 * C_PAIR))[c4];

    f4* o = (f4*)out;
    __builtin_nontemporal_store(v1, o + ((size_t)i * N + j1) * 32 + c4);
    __builtin_nontemporal_store(v2, o + ((size_t)i * N + j2) * 32 + c4);
}

// Fallback (ws too small): direct 4-load version (round-1 kernel)
__global__ __launch_bounds__(256) void rpe_direct(
    const int* __restrict__ res, const int* __restrict__ tok,
    const int* __restrict__ asym, const int* __restrict__ ent,
    const int* __restrict__ sym, const float* __restrict__ W,
    float* __restrict__ out, int N, int blocks_per_row)
{
    const int bid = blockIdx.x;
    const int i  = bid / blocks_per_row;
    const int jb = bid - i * blocks_per_row;
    const int t  = threadIdx.x;
    const int j  = jb * 8 + (t >> 5);
    const int c4 = t & 31;

    const int ri = res[i],  rj = res[j];
    const int ai = asym[i], aj = asym[j];
    const int ei = ent[i],  ej = ent[j];
    const int ti = tok[i],  tj = tok[j];
    const int si = sym[i],  sj = sym[j];

    const bool sr = (ri == rj);
    const bool sc = (ai == aj);
    const bool se = (ei == ej);

    const int idx_pos = sr ? 32 : 65;
    int dt = ti - tj + 32; dt = dt < 0 ? 0 : (dt > 64 ? 64 : dt);
    const int idx_tok = (sr && sc) ? dt : 65;
    int dc = si - sj + 2; dc = dc < 0 ? 0 : (dc > 4 ? 4 : dc);
    const int idx_chain = (!sc) ? dc : 5;

    const f4 p  = ((const f4*)(W + (size_t)idx_pos * C_PAIR))[c4];
    const f4 tk = ((const f4*)(W + (size_t)(66 + idx_tok) * C_PAIR))[c4];
    const f4 e  = ((const f4*)(W + (size_t)132 * C_PAIR))[c4];
    const f4 c  = ((const f4*)(W + (size_t)(133 + idx_chain) * C_PAIR))[c4];
    const float fe = se ? 1.0f : 0.0f;

    f4 r;
    r.x = ((p.x + tk.x) + fe * e.x) + c.x;
    r.y = ((p.y + tk.y) + fe * e.y) + c.y;
    r.z = ((p.z + tk.z) + fe * e.z) + c.z;
    r.w = ((p.w + tk.w) + fe * e.w) + c.w;

    ((f4*)(out + ((size_t)i * N + j) * C_PAIR))[c4] = r;
}

extern "C" void kernel_launch(void* const* d_in, const int* in_sizes, int n_in,
                              void* d_out, int out_size, void* d_ws, size_t ws_size,
                              hipStream_t stream) {
    const int* res  = (const int*)d_in[0];
    const int* tok  = (const int*)d_in[1];
    const int* asym = (const int*)d_in[2];
    const int* ent  = (const int*)d_in[3];
    const int* sym  = (const int*)d_in[4];
    const float* W  = (const float*)d_in[5];
    float* out = (float*)d_out;

    const int N = in_sizes[0];
    const size_t table_bytes = (size_t)N_COMBO * C_PAIR * sizeof(float);

    if (ws_size >= table_bytes && (N % 16) == 0) {
        float* T = (float*)d_ws;
        rpe_combine<<<N_COMBO, 128, 0, stream>>>(W, T);
        const int blocks_per_row = N / 16;
        rpe_apply<<<N * blocks_per_row, 256, 0, stream>>>(res, tok, asym, ent, sym,
                                                          T, out, N, blocks_per_row);
    } else {
        const int blocks_per_row = N / 8;
        rpe_direct<<<N * blocks_per_row, 256, 0, stream>>>(res, tok, asym, ent, sym,
                                                           W, out, N, blocks_per_row);
    }
}